// Round 1
// baseline (253.160 us; speedup 1.0000x reference)
//
#include <hip/hip_runtime.h>
#include <math.h>

// Problem constants (B=8,S=4096,D=1024,E=64,G=4,K=2, temperature=1)
#define TOKENS   32768
#define DDIM     1024
#define BK       32
#define NTILES   32          // DDIM/BK
#define MT       64          // tokens per block
#define NBLOCKS  (TOKENS/MT) // 512

// Output layout (flat float32, tuple concatenated: idx, scores, probs, importance, load)
#define OFF_SCORES 65536
#define OFF_PROBS  131072
#define OFF_IMP    2228224
#define OFF_LOAD   2228288

// LDS word offsets
#define XB0 0        // 64*32
#define WB0 2048     // 72*36
#define XB1 4640
#define WB1 6688     // ends 9280
#define SCRA 0       // 64*73 (aliases dead buffers post-loop)
#define SCRB 4672    // 64*73
#define ELOG 9344    // 64*73
#define CNTO 14016   // 64 ints
#define SMEM_WORDS 14080  // 56.3 KB -> 2 blocks/CU

__global__ __launch_bounds__(256, 2)
void router_kernel(const float* __restrict__ x,
                   const float* __restrict__ Wg,
                   const float* __restrict__ We,
                   float* __restrict__ out,
                   float* __restrict__ ws) {
  __shared__ __attribute__((aligned(16))) float smem[SMEM_WORDS];
  const int tid  = threadIdx.x;
  const int lane = tid & 63;
  const int wv   = tid >> 6;       // wave id = K-split quarter
  const int tn   = lane & 7;       // col group: cols 9*tn..9*tn+8
  const int tm   = lane >> 3;      // token group: tokens 8*tm..8*tm+7
  const int tok0 = blockIdx.x * MT;

  // zero LDS counters + pad weight rows (68..71) of both buffers
  if (tid < 64) ((int*)(smem + CNTO))[tid] = 0;
  if (tid < 144) { smem[WB0 + 68*36 + tid] = 0.f; smem[WB1 + 68*36 + tid] = 0.f; }

  float acc[8][9];
  #pragma unroll
  for (int i = 0; i < 8; ++i)
    #pragma unroll
    for (int j = 0; j < 9; ++j) acc[i][j] = 0.f;

  // ---- staging helpers (256 threads cooperatively stage one BK tile) ----
  auto do_load = [&](int kb, float4& xg0, float4& xg1, float4& wg0, float4& wg1, float4& wg2) {
    { int i2 = tid;       int kq = i2 & 7, t = i2 >> 3;
      xg0 = *(const float4*)(x + (size_t)(tok0 + t)*DDIM + kb + 4*kq); }
    { int i2 = tid + 256; int kq = i2 & 7, t = i2 >> 3;
      xg1 = *(const float4*)(x + (size_t)(tok0 + t)*DDIM + kb + 4*kq); }
    { int i2 = tid;       int kq = i2 & 7, r = i2 >> 3;       // rows 0..31
      wg0 = *(const float4*)(We + (size_t)r*DDIM + kb + 4*kq); }
    { int i2 = tid + 256; int kq = i2 & 7, r = i2 >> 3;       // rows 32..63
      wg1 = *(const float4*)(We + (size_t)r*DDIM + kb + 4*kq); }
    if (tid < 32) { int kq = tid & 7; int r = (tid + 512) >> 3;  // rows 64..67 = groups
      wg2 = *(const float4*)(Wg + (size_t)(r - 64)*DDIM + kb + 4*kq); }
  };
  auto do_store = [&](int xoff, int woff, float4 xg0, float4 xg1, float4 wg0, float4 wg1, float4 wg2) {
    { int i2 = tid;       int kq = i2 & 7, t = i2 >> 3;
      *(float4*)(smem + xoff + t*32 + 4*(kq ^ (t >> 3))) = xg0; }   // XOR-swizzled x quads
    { int i2 = tid + 256; int kq = i2 & 7, t = i2 >> 3;
      *(float4*)(smem + xoff + t*32 + 4*(kq ^ (t >> 3))) = xg1; }
    { int i2 = tid;       int kq = i2 & 7, r = i2 >> 3;
      *(float4*)(smem + woff + r*36 + 4*kq) = wg0; }
    { int i2 = tid + 256; int kq = i2 & 7, r = i2 >> 3;
      *(float4*)(smem + woff + r*36 + 4*kq) = wg1; }
    if (tid < 32) { int kq = tid & 7; int r = (tid + 512) >> 3;
      *(float4*)(smem + woff + r*36 + 4*kq) = wg2; }
  };

  // ---- prologue: stage tile 0 into buf0 ----
  {
    float4 a = {0,0,0,0}, b = a, c = a, d = a, e = a;
    do_load(0, a, b, c, d, e);
    do_store(XB0, WB0, a, b, c, d, e);
  }
  __syncthreads();

  const int xoffs[2] = {XB0, XB1}, woffs[2] = {WB0, WB1};

  // ---- main K loop, double buffered ----
  for (int tile = 0; tile < NTILES; ++tile) {
    const int p = tile & 1;
    float4 xg0 = {0,0,0,0}, xg1 = xg0, wg0 = xg0, wg1 = xg0, wg2 = xg0;
    const bool pf = (tile + 1 < NTILES);
    if (pf) do_load((tile + 1) * BK, xg0, xg1, wg0, wg1, wg2);

    const float* xb = smem + xoffs[p];
    const float* wb = smem + woffs[p];
    #pragma unroll
    for (int qi = 0; qi < 2; ++qi) {
      const int kq = (wv << 1) | qi;             // wave-uniform quad
      const float* xptr = xb + tm*256 + 4*(kq ^ tm);
      const float* wptr = wb + tn*324 + 4*kq;    // 9*36 = 324
      float4 xr[8], wr[9];
      #pragma unroll
      for (int i = 0; i < 8; ++i) xr[i] = *(const float4*)(xptr + i*32);
      #pragma unroll
      for (int j = 0; j < 9; ++j) wr[j] = *(const float4*)(wptr + j*36);
      #pragma unroll
      for (int i = 0; i < 8; ++i)
        #pragma unroll
        for (int j = 0; j < 9; ++j) {
          acc[i][j] = fmaf(xr[i].x, wr[j].x, acc[i][j]);
          acc[i][j] = fmaf(xr[i].y, wr[j].y, acc[i][j]);
          acc[i][j] = fmaf(xr[i].z, wr[j].z, acc[i][j]);
          acc[i][j] = fmaf(xr[i].w, wr[j].w, acc[i][j]);
        }
    }
    if (pf) do_store(xoffs[p ^ 1], woffs[p ^ 1], xg0, xg1, wg0, wg1, wg2);
    __syncthreads();
  }

  // ---- cross-wave K-split reduction (waves 0..3 hold partial sums) ----
  {
    float* A  = smem + SCRA;
    float* Bv = smem + SCRB;
    const int rb = lane * 73;
    if (wv == 1) {
      #pragma unroll
      for (int i = 0; i < 8; ++i)
        #pragma unroll
        for (int j = 0; j < 9; ++j) A[rb + i*9 + j] = acc[i][j];
    }
    if (wv == 3) {
      #pragma unroll
      for (int i = 0; i < 8; ++i)
        #pragma unroll
        for (int j = 0; j < 9; ++j) Bv[rb + i*9 + j] = acc[i][j];
    }
    __syncthreads();
    if (wv == 0) {
      #pragma unroll
      for (int i = 0; i < 8; ++i)
        #pragma unroll
        for (int j = 0; j < 9; ++j) acc[i][j] += A[rb + i*9 + j];
    }
    if (wv == 2) {
      #pragma unroll
      for (int i = 0; i < 8; ++i)
        #pragma unroll
        for (int j = 0; j < 9; ++j) acc[i][j] += Bv[rb + i*9 + j];
    }
    __syncthreads();
    if (wv == 2) {
      #pragma unroll
      for (int i = 0; i < 8; ++i)
        #pragma unroll
        for (int j = 0; j < 9; ++j) A[rb + i*9 + j] = acc[i][j];
    }
    __syncthreads();
    if (wv == 0) {
      float* el = smem + ELOG;
      #pragma unroll
      for (int i = 0; i < 8; ++i)
        #pragma unroll
        for (int j = 0; j < 9; ++j) {
          const float v = acc[i][j] + A[rb + i*9 + j];
          el[(tm*8 + i)*73 + (tn*9 + j)] = v;   // cols 0..63 experts, 64..67 groups, 68..71 pad
        }
    }
    __syncthreads();
  }

  // ---- epilogue: one token per thread (tid<64) ----
  float* el  = smem + ELOG;
  int*   cnt = (int*)(smem + CNTO);
  if (tid < 64) {
    const int t = tid;
    float* row = el + t*73;
    // group argmax (softmax is monotone; first-occurrence via strict >)
    const float g0 = row[64], g1 = row[65], g2 = row[66], g3 = row[67];
    int g = 0; float gb = g0;
    if (g1 > gb) { g = 1; gb = g1; }
    if (g2 > gb) { g = 2; gb = g2; }
    if (g3 > gb) { g = 3; gb = g3; }
    const int base = g << 4;
    float l[16];
    #pragma unroll
    for (int e = 0; e < 16; ++e) l[e] = row[base + e];
    // top-1 (first occurrence) and top-2 (next index on ties) — matches lax.top_k
    int i1 = 0; float v1 = l[0];
    #pragma unroll
    for (int e = 1; e < 16; ++e) if (l[e] > v1) { i1 = e; v1 = l[e]; }
    int i2 = -1; float v2 = 0.f;
    #pragma unroll
    for (int e = 0; e < 16; ++e) {
      if (e == i1) continue;
      if (i2 < 0 || l[e] > v2) { i2 = e; v2 = l[e]; }
    }
    // masked softmax over selected group (masked logits are float-min => exactly 0 prob)
    float pr[16]; float s = 0.f;
    #pragma unroll
    for (int e = 0; e < 16; ++e) { pr[e] = expf(l[e] - v1); s += pr[e]; }
    const float inv = 1.f / s;
    #pragma unroll
    for (int c = 0; c < 64; ++c) row[c] = 0.f;
    #pragma unroll
    for (int e = 0; e < 16; ++e) row[base + e] = pr[e] * inv;
    // outputs: idx (as float), scores = softmax([v1,v2])
    const size_t T = (size_t)tok0 + t;
    out[2*T]     = (float)(base + i1);
    out[2*T + 1] = (float)(base + i2);
    const float e2 = expf(v2 - v1);
    const float si = 1.f / (1.f + e2);
    out[OFF_SCORES + 2*T]     = si;
    out[OFF_SCORES + 2*T + 1] = e2 * si;
    atomicAdd(&cnt[base + i1], 1);
    atomicAdd(&cnt[base + i2], 1);
  }
  __syncthreads();

  // coalesced probs_full write
  for (int i = tid; i < MT*64; i += 256) {
    const int t = i >> 6, c = i & 63;
    out[OFF_PROBS + (((size_t)(tok0 + t)) << 6) + c] = el[t*73 + c];
  }
  // block-partial importance & counts -> global atomics
  if (tid < 64) {
    const int e = tid;
    float s = 0.f;
    for (int t = 0; t < MT; ++t) s += el[t*73 + e];
    atomicAdd(&ws[e], s);
    atomicAdd(&ws[64 + e], (float)cnt[e]);
  }
}

__global__ void finalize_kernel(const float* __restrict__ ws, float* __restrict__ out) {
  const int e = threadIdx.x;
  if (e < 64) {
    out[OFF_IMP  + e] = ws[e]      * (1.0f / 32768.0f);   // mean over B*S
    out[OFF_LOAD + e] = ws[64 + e] * (1.0f / 65536.0f);   // counts sum == B*S*K
  }
}

extern "C" void kernel_launch(void* const* d_in, const int* in_sizes, int n_in,
                              void* d_out, int out_size, void* d_ws, size_t ws_size,
                              hipStream_t stream) {
  (void)in_sizes; (void)n_in; (void)out_size; (void)ws_size;
  const float* x  = (const float*)d_in[0];   // [8,4096,1024]
  const float* Wg = (const float*)d_in[1];   // [4,1024]
  const float* We = (const float*)d_in[2];   // [64,1024]
  float* out = (float*)d_out;
  float* ws  = (float*)d_ws;                 // [0..63] importance sums, [64..127] counts
  hipMemsetAsync(d_ws, 0, 128 * sizeof(float), stream);
  hipLaunchKernelGGL(router_kernel, dim3(NBLOCKS), dim3(256), 0, stream, x, Wg, We, out, ws);
  hipLaunchKernelGGL(finalize_kernel, dim3(1), dim3(64), 0, stream, ws, out);
}

// Round 3
// 221.684 us; speedup vs baseline: 1.1420x; 1.1420x over previous
//
#include <hip/hip_runtime.h>
#include <math.h>

// Problem constants (B=8,S=4096,D=1024,E=64,G=4,K=2, temperature=1)
#define TOKENS   32768
#define DDIM     1024
#define NBLOCKS  512          // 64 tokens per block

// Output layout (flat float32, tuple concat: idx, scores, probs, importance, load)
#define OFF_SCORES 65536
#define OFF_PROBS  131072
#define OFF_IMP    2228224
#define OFF_LOAD   2228288

typedef __attribute__((ext_vector_type(8))) short  short8;  // 8 bf16 = 4 VGPR (MFMA A/B frag)
typedef __attribute__((ext_vector_type(4))) float  f32x4;   // MFMA C/D frag
typedef __attribute__((ext_vector_type(4))) int    intx4;

// Pre-split W fragments: [ks(32)][nt(5)][s(3)][lane(64)] x 16B. 480 KB, L2-resident.
// Rows 0..63 = experts, 64..67 = groups, 68..79 = zero pad.
__device__ __attribute__((aligned(16))) short wfrag[32 * 5 * 3 * 64 * 8];

// bf16 round-to-nearest-even of x, returned as the fp32 bit pattern.
__device__ inline unsigned rne_hi(float x) {
  unsigned u = __float_as_uint(x);
  unsigned r = u + 0x7fffu + ((u >> 16) & 1u);
  return r & 0xffff0000u;
}

// Split x (fp32) into 3 RNE-bf16 terms: x = a1 + a2 + a3 + O(2^-27 |x|).
// Residual subtractions are exact (Sterbenz: a_i within factor-2 of remainder).
__device__ inline void split3(const float* xv, short8& f1, short8& f2, short8& f3) {
  int o1[4], o2[4], o3[4];
  #pragma unroll
  for (int p = 0; p < 4; ++p) {
    float x0 = xv[2*p], x1 = xv[2*p+1];
    unsigned h0 = rne_hi(x0), h1 = rne_hi(x1);
    o1[p] = (int)((h0 >> 16) | (h1 & 0xffff0000u));
    float r0 = x0 - __uint_as_float(h0);
    float r1 = x1 - __uint_as_float(h1);
    unsigned g0 = rne_hi(r0), g1 = rne_hi(r1);
    o2[p] = (int)((g0 >> 16) | (g1 & 0xffff0000u));
    float s0 = r0 - __uint_as_float(g0);
    float s1 = r1 - __uint_as_float(g1);
    unsigned w0 = rne_hi(s0), w1 = rne_hi(s1);
    o3[p] = (int)((w0 >> 16) | (w1 & 0xffff0000u));
  }
  intx4 t1 = {o1[0], o1[1], o1[2], o1[3]};
  intx4 t2 = {o2[0], o2[1], o2[2], o2[3]};
  intx4 t3 = {o3[0], o3[1], o3[2], o3[3]};
  f1 = __builtin_bit_cast(short8, t1);
  f2 = __builtin_bit_cast(short8, t2);
  f3 = __builtin_bit_cast(short8, t3);
}

// Build W fragment splits. 160 blocks (nt*32+ks) x 64 threads.
__global__ void prep_kernel(const float* __restrict__ Wg, const float* __restrict__ We) {
  const int nt   = blockIdx.x >> 5;   // 0..4
  const int ks   = blockIdx.x & 31;   // 0..31
  const int lane = threadIdx.x & 63;
  const int row  = nt * 16 + (lane & 15);
  const int k0   = ks * 32 + (lane >> 4) * 8;
  float xv[8];
  #pragma unroll
  for (int j = 0; j < 8; ++j) {
    float v = 0.f;
    if (row < 64)      v = We[(size_t)row * DDIM + k0 + j];
    else if (row < 68) v = Wg[(size_t)(row - 64) * DDIM + k0 + j];
    xv[j] = v;
  }
  short8 f1, f2, f3;
  split3(xv, f1, f2, f3);
  short8* dst = (short8*)wfrag + (((size_t)ks * 5 + nt) * 3) * 64 + lane;
  dst[0]   = f1;
  dst[64]  = f2;
  dst[128] = f3;
}

__global__ __launch_bounds__(256, 2)
void router_kernel(const float* __restrict__ x,
                   float* __restrict__ out,
                   float* __restrict__ ws) {
  __shared__ float el[64 * 88];   // logits [token][col], stride 88 (2-way bank alias = free)
  __shared__ int   cnt[64];
  const int tid    = threadIdx.x;
  const int lane   = tid & 63;
  const int wv     = tid >> 6;
  const int tokgrp = wv >> 1;      // 0/1: which 32-token half of the block
  const int khalf  = wv & 1;       // 0/1: which 512-wide K half
  const int quad   = lane >> 4;
  const int m      = lane & 15;
  const int tokblk = blockIdx.x * 64;
  const int tok0   = tokblk + tokgrp * 32;

  if (tid < 64) cnt[tid] = 0;

  // MFMA A-operand gather: lane holds A[row=m][k=quad*8+j]; two 16-token tiles.
  const float* ap0 = x + (size_t)(tok0 + m) * DDIM + khalf * 512 + quad * 8;
  const float* ap1 = ap0 + (size_t)16 * DDIM;

  f32x4 ahi[2][5], alo[2][5];
  #pragma unroll
  for (int mt = 0; mt < 2; ++mt)
    #pragma unroll
    for (int nt = 0; nt < 5; ++nt) { ahi[mt][nt] = 0.f; alo[mt][nt] = 0.f; }

  for (int ks = 0; ks < 16; ++ks) {
    const float* p0 = ap0 + ks * 32;
    const float* p1 = ap1 + ks * 32;
    float4 a0 = *(const float4*)(p0), a1 = *(const float4*)(p0 + 4);
    float4 a2 = *(const float4*)(p1), a3 = *(const float4*)(p1 + 4);

    // B fragments for this K-step (coalesced 1KB/instr, L2-hot)
    const short8* bp = (const short8*)wfrag + ((size_t)(khalf * 16 + ks) * 15) * 64 + lane;
    short8 fb[5][3];
    #pragma unroll
    for (int nt = 0; nt < 5; ++nt) {
      fb[nt][0] = bp[nt * 192];
      fb[nt][1] = bp[nt * 192 + 64];
      fb[nt][2] = bp[nt * 192 + 128];
    }
    short8 fa[2][3];
    {
      float av[8] = {a0.x, a0.y, a0.z, a0.w, a1.x, a1.y, a1.z, a1.w};
      split3(av, fa[0][0], fa[0][1], fa[0][2]);
      float bv[8] = {a2.x, a2.y, a2.z, a2.w, a3.x, a3.y, a3.z, a3.w};
      split3(bv, fa[1][0], fa[1][1], fa[1][2]);
    }
    // 8-pass split MFMA: a1b1 -> hi; all cross terms -> lo (only a3b3 dropped)
    #pragma unroll
    for (int nt = 0; nt < 5; ++nt)
      #pragma unroll
      for (int mt = 0; mt < 2; ++mt) {
        ahi[mt][nt] = __builtin_amdgcn_mfma_f32_16x16x32_bf16(fa[mt][0], fb[nt][0], ahi[mt][nt], 0, 0, 0);
        f32x4 c = alo[mt][nt];
        c = __builtin_amdgcn_mfma_f32_16x16x32_bf16(fa[mt][0], fb[nt][1], c, 0, 0, 0);
        c = __builtin_amdgcn_mfma_f32_16x16x32_bf16(fa[mt][1], fb[nt][0], c, 0, 0, 0);
        c = __builtin_amdgcn_mfma_f32_16x16x32_bf16(fa[mt][1], fb[nt][1], c, 0, 0, 0);
        c = __builtin_amdgcn_mfma_f32_16x16x32_bf16(fa[mt][0], fb[nt][2], c, 0, 0, 0);
        c = __builtin_amdgcn_mfma_f32_16x16x32_bf16(fa[mt][2], fb[nt][0], c, 0, 0, 0);
        c = __builtin_amdgcn_mfma_f32_16x16x32_bf16(fa[mt][1], fb[nt][2], c, 0, 0, 0);
        c = __builtin_amdgcn_mfma_f32_16x16x32_bf16(fa[mt][2], fb[nt][1], c, 0, 0, 0);
        alo[mt][nt] = c;
      }
  }

  // ---- K-half reduction via LDS. C/D layout: col(n)=lane&15, row(m)=quad*4+reg ----
  if (khalf == 1) {
    #pragma unroll
    for (int mt = 0; mt < 2; ++mt)
      #pragma unroll
      for (int nt = 0; nt < 5; ++nt)
        #pragma unroll
        for (int r = 0; r < 4; ++r)
          el[(tokgrp * 32 + mt * 16 + quad * 4 + r) * 88 + nt * 16 + m] =
              ahi[mt][nt][r] + alo[mt][nt][r];
  }
  __syncthreads();
  if (khalf == 0) {
    #pragma unroll
    for (int mt = 0; mt < 2; ++mt)
      #pragma unroll
      for (int nt = 0; nt < 5; ++nt)
        #pragma unroll
        for (int r = 0; r < 4; ++r) {
          const int idx = (tokgrp * 32 + mt * 16 + quad * 4 + r) * 88 + nt * 16 + m;
          el[idx] += ahi[mt][nt][r] + alo[mt][nt][r];
        }
  }
  __syncthreads();

  // ---- epilogue: one token per thread (tid<64) ----
  if (tid < 64) {
    const int t = tid;
    float* row = el + t * 88;
    const float g0 = row[64], g1 = row[65], g2 = row[66], g3 = row[67];
    int g = 0; float gb = g0;
    if (g1 > gb) { g = 1; gb = g1; }
    if (g2 > gb) { g = 2; gb = g2; }
    if (g3 > gb) { g = 3; gb = g3; }
    const int base = g << 4;
    float l[16];
    #pragma unroll
    for (int e = 0; e < 16; ++e) l[e] = row[base + e];
    int i1 = 0; float v1 = l[0];
    #pragma unroll
    for (int e = 1; e < 16; ++e) if (l[e] > v1) { i1 = e; v1 = l[e]; }
    int i2 = -1; float v2 = 0.f;
    #pragma unroll
    for (int e = 0; e < 16; ++e) {
      if (e == i1) continue;
      if (i2 < 0 || l[e] > v2) { i2 = e; v2 = l[e]; }
    }
    float pr[16]; float s = 0.f;
    #pragma unroll
    for (int e = 0; e < 16; ++e) { pr[e] = expf(l[e] - v1); s += pr[e]; }
    const float inv = 1.f / s;
    #pragma unroll
    for (int c = 0; c < 64; ++c) row[c] = 0.f;
    #pragma unroll
    for (int e = 0; e < 16; ++e) row[base + e] = pr[e] * inv;
    const size_t T = (size_t)tokblk + t;
    out[2*T]     = (float)(base + i1);
    out[2*T + 1] = (float)(base + i2);
    const float e2 = expf(v2 - v1);
    const float si = 1.f / (1.f + e2);
    out[OFF_SCORES + 2*T]     = si;
    out[OFF_SCORES + 2*T + 1] = e2 * si;
    atomicAdd(&cnt[base + i1], 1);
    atomicAdd(&cnt[base + i2], 1);
  }
  __syncthreads();

  // coalesced probs_full write
  for (int i = tid; i < 64 * 64; i += 256) {
    const int t = i >> 6, c = i & 63;
    out[OFF_PROBS + (((size_t)(tokblk + t)) << 6) + c] = el[t * 88 + c];
  }
  // block-partial importance & counts -> global atomics
  if (tid < 64) {
    const int e = tid;
    float s = 0.f;
    for (int t = 0; t < 64; ++t) s += el[t * 88 + e];
    atomicAdd(&ws[e], s);
    atomicAdd(&ws[64 + e], (float)cnt[e]);
  }
}

__global__ void finalize_kernel(const float* __restrict__ ws, float* __restrict__ out) {
  const int e = threadIdx.x;
  if (e < 64) {
    out[OFF_IMP  + e] = ws[e]      * (1.0f / 32768.0f);
    out[OFF_LOAD + e] = ws[64 + e] * (1.0f / 65536.0f);
  }
}

extern "C" void kernel_launch(void* const* d_in, const int* in_sizes, int n_in,
                              void* d_out, int out_size, void* d_ws, size_t ws_size,
                              hipStream_t stream) {
  (void)in_sizes; (void)n_in; (void)out_size; (void)ws_size;
  const float* x  = (const float*)d_in[0];   // [8,4096,1024]
  const float* Wg = (const float*)d_in[1];   // [4,1024]
  const float* We = (const float*)d_in[2];   // [64,1024]
  float* out = (float*)d_out;
  float* ws  = (float*)d_ws;                 // [0..63] importance sums, [64..127] counts
  hipMemsetAsync(d_ws, 0, 128 * sizeof(float), stream);
  hipLaunchKernelGGL(prep_kernel, dim3(160), dim3(64), 0, stream, Wg, We);
  hipLaunchKernelGGL(router_kernel, dim3(NBLOCKS), dim3(256), 0, stream, x, out, ws);
  hipLaunchKernelGGL(finalize_kernel, dim3(1), dim3(64), 0, stream, ws, out);
}